// Round 1
// baseline (727.334 us; speedup 1.0000x reference)
//
#include <hip/hip_runtime.h>
#include <math.h>

#define BLOCK 256
#define TILE_R 64
#define LIN 592

// smooth_leaky_relu(x) = 0.6x + 0.4x(2*sigmoid(x)-1) = x*(0.2 + 0.8*sigmoid(x))
__device__ __forceinline__ float slr(float v) {
    float s = 1.0f / (1.0f + __expf(-v));
    return v * (0.2f + 0.8f * s);
}

// One segment: stage x[:, C0 : C0+MUL*D] for 64 rows into LDS (padded, odd
// stride -> conflict-free lanes-as-rows reads), each wave computes MUL/4
// contiguous outputs o for all 64 rows, weights via wave-uniform s_load.
template<int MUL, int D, int C0, int MB, bool ACT>
__device__ __forceinline__ void seg_compute(
    float* __restrict__ xs,
    const float* __restrict__ x,
    const float* __restrict__ w,   // [MUL, MUL] row-major (o, m)
    const float* __restrict__ b,   // [MUL]
    float* __restrict__ out,
    int n0, int N, int tid, int lane, int wv)
{
    constexpr int SEGC = MUL * D;       // columns in this segment
    constexpr int S    = SEGC + 1;      // LDS row stride (odd -> no bank conflict)
    constexpr int OPW  = MUL / 4;       // outputs (o) per wave

    // ---- stage: global -> LDS (coalesced float4 reads) ----
    constexpr int F4_PER_ROW = SEGC / 4;
    constexpr int F4 = TILE_R * F4_PER_ROW;
    #pragma unroll 1
    for (int i = tid; i < F4; i += BLOCK) {
        int r  = i / F4_PER_ROW;
        int cb = i - r * F4_PER_ROW;
        int gr = n0 + r;
        float4 v = make_float4(0.f, 0.f, 0.f, 0.f);
        if (gr < N) v = *(const float4*)(x + (size_t)gr * LIN + C0 + cb * 4);
        float* dst = xs + r * S + cb * 4;
        dst[0] = v.x; dst[1] = v.y; dst[2] = v.z; dst[3] = v.w;
    }
    __syncthreads();

    // ---- compute: acc[oo][j] = b[o] + sum_m w[o][m] * xs[lane][m*D+j] ----
    float acc[OPW * D];
    #pragma unroll
    for (int oo = 0; oo < OPW; ++oo) {
        float bv = b[wv * OPW + oo];            // uniform -> s_load
        #pragma unroll
        for (int j = 0; j < D; ++j) acc[oo * D + j] = bv;
    }

    const float* xrow = xs + lane * S;
    #pragma unroll 1
    for (int mb = 0; mb < MUL; mb += MB) {
        float xv[MB * D];
        #pragma unroll
        for (int k = 0; k < MB * D; ++k) xv[k] = xrow[mb * D + k];
        #pragma unroll
        for (int oo = 0; oo < OPW; ++oo) {
            const float* wr = w + (wv * OPW + oo) * MUL + mb;  // uniform -> s_load
            #pragma unroll
            for (int mm = 0; mm < MB; ++mm) {
                float wval = wr[mm];
                #pragma unroll
                for (int j = 0; j < D; ++j)
                    acc[oo * D + j] = fmaf(wval, xv[mm * D + j], acc[oo * D + j]);
            }
        }
    }

    if (ACT) {
        #pragma unroll
        for (int i = 0; i < OPW * D; ++i) acc[i] = slr(acc[i]);
    }

    // ---- store: wave's outputs are contiguous c-range -> float4 from regs ----
    int row = n0 + lane;
    if (row < N) {
        float4* op = (float4*)(out + (size_t)row * LIN + C0 + wv * (OPW * D));
        #pragma unroll
        for (int i = 0; i < OPW * D / 4; ++i)
            op[i] = make_float4(acc[4*i], acc[4*i+1], acc[4*i+2], acc[4*i+3]);
    }
    __syncthreads();   // xs reused by next segment
}

__global__ __launch_bounds__(BLOCK, 2)
void irreps_kernel(const float* __restrict__ x,
                   const float* __restrict__ w0, const float* __restrict__ w1,
                   const float* __restrict__ w2, const float* __restrict__ w3,
                   const float* __restrict__ b0, const float* __restrict__ b1,
                   const float* __restrict__ b2, const float* __restrict__ b3,
                   float* __restrict__ out, int N)
{
    // max segment LDS: seg1 = 64 rows * (192+1) floats = 49408 B -> 3 blocks/CU
    __shared__ float xs[TILE_R * 193];
    int tid  = threadIdx.x;
    int lane = tid & 63;
    int wv   = __builtin_amdgcn_readfirstlane(tid >> 6);  // wave id, provably uniform
    int n0   = blockIdx.x * TILE_R;

    seg_compute<128, 1,   0, 16, true >(xs, x, w0, b0, out, n0, N, tid, lane, wv);
    seg_compute< 64, 3, 128,  8, false>(xs, x, w1, b1, out, n0, N, tid, lane, wv);
    seg_compute< 32, 5, 320,  4, false>(xs, x, w2, b2, out, n0, N, tid, lane, wv);
    seg_compute< 16, 7, 480,  4, false>(xs, x, w3, b3, out, n0, N, tid, lane, wv);
}

extern "C" void kernel_launch(void* const* d_in, const int* in_sizes, int n_in,
                              void* d_out, int out_size, void* d_ws, size_t ws_size,
                              hipStream_t stream) {
    const float* x  = (const float*)d_in[0];
    const float* w0 = (const float*)d_in[1];
    const float* w1 = (const float*)d_in[2];
    const float* w2 = (const float*)d_in[3];
    const float* w3 = (const float*)d_in[4];
    const float* b0 = (const float*)d_in[5];
    const float* b1 = (const float*)d_in[6];
    const float* b2 = (const float*)d_in[7];
    const float* b3 = (const float*)d_in[8];
    float* out = (float*)d_out;

    int N = in_sizes[0] / LIN;                 // 100000
    int grid = (N + TILE_R - 1) / TILE_R;      // 1563
    irreps_kernel<<<grid, BLOCK, 0, stream>>>(x, w0, w1, w2, w3,
                                              b0, b1, b2, b3, out, N);
}

// Round 2
// 511.373 us; speedup vs baseline: 1.4223x; 1.4223x over previous
//
#include <hip/hip_runtime.h>
#include <math.h>

#define BLOCK 512
#define TILE_R 64
#define LIN 592
#define NTILES_LDS (TILE_R * 193)   // worst segment: 64 rows * (192+1) floats = 49.4 KB

// smooth_leaky_relu(x) = x*(0.2 + 0.8*sigmoid(x))
__device__ __forceinline__ float slr(float v) {
    float s = 1.0f / (1.0f + __expf(-v));
    return v * (0.2f + 0.8f * s);
}

// One block handles one (row-tile, segment) pair: stage 64 rows of the segment
// into LDS (odd stride -> conflict-free lanes-as-rows reads), ONE barrier, then
// each of 8 waves computes MUL/8 contiguous outputs o for its lane-row.
template<int MUL, int D, int C0, int MB, bool ACT>
__device__ __forceinline__ void seg_compute(
    float* __restrict__ xs,
    const float* __restrict__ x,
    const float* __restrict__ w,   // [MUL, MUL] row-major (o, m)
    const float* __restrict__ b,   // [MUL]
    float* __restrict__ out,
    int n0, int N, int tid, int lane, int wv)
{
    constexpr int SEGC = MUL * D;       // columns in this segment
    constexpr int S    = SEGC + 1;      // LDS row stride (odd -> bank-spread)
    constexpr int OPW  = MUL / 8;       // outputs (o) per wave (8 waves)

    // ---- stage: global -> LDS, coalesced float4 ----
    constexpr int CH = SEGC / 4;        // float4 chunks per row
    constexpr int F4 = TILE_R * CH;
    #pragma unroll 1
    for (int i = tid; i < F4; i += BLOCK) {
        int r  = i / CH;                // constexpr divisor -> magic mul
        int cb = i - r * CH;
        int gr = n0 + r;
        float4 v = make_float4(0.f, 0.f, 0.f, 0.f);
        if (gr < N) v = *(const float4*)(x + (size_t)gr * LIN + C0 + cb * 4);
        float* dst = xs + r * S + cb * 4;
        dst[0] = v.x; dst[1] = v.y; dst[2] = v.z; dst[3] = v.w;
    }
    __syncthreads();

    // ---- compute: acc[oo][j] = b[o] + sum_m w[o][m] * xs[lane][m*D+j] ----
    float acc[OPW * D];
    #pragma unroll
    for (int oo = 0; oo < OPW; ++oo) {
        float bv = b[wv * OPW + oo];            // wave-uniform -> s_load
        #pragma unroll
        for (int j = 0; j < D; ++j) acc[oo * D + j] = bv;
    }

    const float* xrow = xs + lane * S;
    #pragma unroll 1
    for (int mb = 0; mb < MUL; mb += MB) {
        float xv[MB * D];
        #pragma unroll
        for (int k = 0; k < MB * D; ++k) xv[k] = xrow[mb * D + k];
        #pragma unroll
        for (int oo = 0; oo < OPW; ++oo) {
            const float* wr = w + (wv * OPW + oo) * MUL + mb;  // uniform -> s_load
            #pragma unroll
            for (int mm = 0; mm < MB; ++mm) {
                float wval = wr[mm];
                #pragma unroll
                for (int j = 0; j < D; ++j)
                    acc[oo * D + j] = fmaf(wval, xv[mm * D + j], acc[oo * D + j]);
            }
        }
    }

    if (ACT) {
        #pragma unroll
        for (int i = 0; i < OPW * D; ++i) acc[i] = slr(acc[i]);
    }

    // ---- store: wave's outputs are a contiguous c-range per row ----
    int row = n0 + lane;
    if (row < N) {
        float* op = out + (size_t)row * LIN + C0 + wv * (OPW * D);
        #pragma unroll
        for (int i = 0; i < OPW * D; ++i) op[i] = acc[i];
    }
}

__global__ __launch_bounds__(BLOCK, 6)
void irreps_kernel(const float* __restrict__ x,
                   const float* __restrict__ w0, const float* __restrict__ w1,
                   const float* __restrict__ w2, const float* __restrict__ w3,
                   const float* __restrict__ b0, const float* __restrict__ b1,
                   const float* __restrict__ b2, const float* __restrict__ b3,
                   float* __restrict__ out, int N)
{
    __shared__ float xs[NTILES_LDS];    // 49.4 KB -> 3 blocks/CU, 24 waves/CU
    int tid  = threadIdx.x;
    int lane = tid & 63;
    int wv   = __builtin_amdgcn_readfirstlane(tid >> 6);  // wave id, uniform
    int n0   = blockIdx.x * TILE_R;

    switch (blockIdx.y) {
    case 0: seg_compute<128, 1,   0, 16, true >(xs, x, w0, b0, out, n0, N, tid, lane, wv); break;
    case 1: seg_compute< 64, 3, 128,  8, false>(xs, x, w1, b1, out, n0, N, tid, lane, wv); break;
    case 2: seg_compute< 32, 5, 320,  4, false>(xs, x, w2, b2, out, n0, N, tid, lane, wv); break;
    default:seg_compute< 16, 7, 480,  4, false>(xs, x, w3, b3, out, n0, N, tid, lane, wv); break;
    }
}

extern "C" void kernel_launch(void* const* d_in, const int* in_sizes, int n_in,
                              void* d_out, int out_size, void* d_ws, size_t ws_size,
                              hipStream_t stream) {
    const float* x  = (const float*)d_in[0];
    const float* w0 = (const float*)d_in[1];
    const float* w1 = (const float*)d_in[2];
    const float* w2 = (const float*)d_in[3];
    const float* w3 = (const float*)d_in[4];
    const float* b0 = (const float*)d_in[5];
    const float* b1 = (const float*)d_in[6];
    const float* b2 = (const float*)d_in[7];
    const float* b3 = (const float*)d_in[8];
    float* out = (float*)d_out;

    int N = in_sizes[0] / LIN;                      // 100000
    dim3 grid((N + TILE_R - 1) / TILE_R, 4);        // 1563 x 4 independent blocks
    irreps_kernel<<<grid, BLOCK, 0, stream>>>(x, w0, w1, w2, w3,
                                              b0, b1, b2, b3, out, N);
}